// Round 2
// baseline (163.036 us; speedup 1.0000x reference)
//
#include <hip/hip_runtime.h>

#define KSZ 5
#define KK  25
#define NC  4
#define NH  128
#define NW  128
#define NB  16
#define NCH_UNET 101
#define HW  (NH*NW)

// Block: 32 (w) x 8 (h) = 256 threads; each thread = 1 pixel, all 4 channels.
// x tile staged in LDS with 2-halo, zero padded (SAME). 4*12*36*4B = 6912 B.
__global__ __launch_bounds__(256)
void DefocusLKPN_kernel(const float* __restrict__ x,
                        const float* __restrict__ defocus,
                        const float* __restrict__ unet,
                        const float* __restrict__ alpha_p,
                        float* __restrict__ out)
{
    __shared__ float sx[NC][12][36];

    const int tx  = threadIdx.x;           // 0..31
    const int ty  = threadIdx.y;           // 0..7
    const int tid = ty * 32 + tx;
    const int w0  = blockIdx.x * 32;
    const int h0  = blockIdx.y * 8;
    const int b   = blockIdx.z;

    // ---- cooperative x-tile load (zero-padded halo) ----
    const float* xb = x + (size_t)b * NC * HW;
    #pragma unroll
    for (int i = tid; i < NC * 12 * 36; i += 256) {
        int c   = i / (12 * 36);
        int rem = i - c * (12 * 36);
        int r   = rem / 36;
        int col = rem - r * 36;
        int gh = h0 - 2 + r;
        int gw = w0 - 2 + col;
        float v = 0.0f;
        if (gh >= 0 && gh < NH && gw >= 0 && gw < NW)
            v = xb[c * HW + gh * NW + gw];
        sx[c][r][col] = v;
    }
    __syncthreads();

    const int h   = h0 + ty;
    const int w   = w0 + tx;
    const int pix = h * NW + w;

    const float alpha = alpha_p[0];
    const float dmap  = defocus[(size_t)b * HW + pix];
    const float* up   = unet + (size_t)b * NCH_UNET * HW + pix;

    // radius = clip(alpha*defocus + tanh(unet[100]), 0, MAX_RADIUS)
    const float dr = tanhf(up[100 * HW]);
    float radius = alpha * dmap + dr;
    radius = fminf(fmaxf(radius, 0.0f), 3.0f);

    // disk mask: sigmoid(BETA * (radius - dist_k)); dist folds to constants
    float mask[KK];
    #pragma unroll
    for (int k = 0; k < KK; ++k) {
        const int dy = k / 5 - 2;
        const int dx = k % 5 - 2;
        const float dist = sqrtf((float)(dy * dy + dx * dx));
        const float t = 5.0f * (radius - dist);
        mask[k] = 1.0f / (1.0f + __expf(-t));
    }

    float* op = out + (size_t)b * NC * HW + pix;

    #pragma unroll
    for (int c = 0; c < NC; ++c) {
        // load 25 logits (wave-coalesced, stride HW between taps)
        float l[KK];
        float m = -1e30f;
        #pragma unroll
        for (int k = 0; k < KK; ++k) {
            l[k] = up[(c * KK + k) * HW];
            m = fmaxf(m, l[k]);
        }
        // softmax denominator cancels:
        // mk = e_k*mask_k / max(S, EPS*Z), e_k = exp(l_k - m)
        float Z = 0.0f, S = 0.0f;
        #pragma unroll
        for (int k = 0; k < KK; ++k) {
            float e  = __expf(l[k] - m);
            float em = e * mask[k];
            Z += e;
            S += em;
            l[k] = em;
        }
        const float inv = 1.0f / fmaxf(S, 1e-6f * Z);

        float acc = 0.0f;
        #pragma unroll
        for (int k = 0; k < KK; ++k) {
            acc += l[k] * sx[c][ty + k / 5][tx + k % 5];
        }
        op[c * HW] = acc * inv + sx[c][ty + 2][tx + 2];
    }
}

extern "C" void kernel_launch(void* const* d_in, const int* in_sizes, int n_in,
                              void* d_out, int out_size, void* d_ws, size_t ws_size,
                              hipStream_t stream) {
    const float* x       = (const float*)d_in[0];
    const float* defocus = (const float*)d_in[1];
    const float* unet    = (const float*)d_in[2];
    const float* alpha   = (const float*)d_in[3];
    float* out = (float*)d_out;

    dim3 block(32, 8, 1);
    dim3 grid(NW / 32, NH / 8, NB);
    DefocusLKPN_kernel<<<grid, block, 0, stream>>>(x, defocus, unet, alpha, out);
}